// Round 3
// baseline (1070.513 us; speedup 1.0000x reference)
//
#include <hip/hip_runtime.h>

// Problem constants (fixed by the reference).
#define N_FEAT  200000
#define DIM     512
#define KPROTO  64
#define CHUNK   32
#define NCHUNKS (N_FEAT / CHUNK)   // 6250, exact
#define APITCH  520                // f16 elems per LDS row: 1040B -> 2-way bank alias (free)
#define SPITCH  65                 // sims pitch: 65 dwords -> conflict-free row scans

typedef _Float16 f16;
typedef _Float16 f16x8 __attribute__((ext_vector_type(8)));
typedef _Float16 f16x4 __attribute__((ext_vector_type(4)));
typedef float    f32x4 __attribute__((ext_vector_type(4)));

// ws layout (bytes):
//   [0,      65536)  : p_h    f16  [64][512]   normalized prototypes
//   [65536,  65792)  : counts int  [64]
//   [65792,  265792) : asg    u8   [200000]
//   [266240, ...)    : STORE path: part f32 [nb][8192]  per-block partials
//                      ATOMIC fallback: sums f32 [64][512]
#define WS_PH     0
#define WS_COUNTS 65536
#define WS_ASG    65792
#define WS_BULK   266240

// ---------------------------------------------------------------- proto prep
__global__ __launch_bounds__(256) void proto_prep(const float* __restrict__ P,
                                                  f16* __restrict__ Ph) {
    __shared__ float red[4];
    __shared__ float s_scale;
    int k = blockIdx.x;
    int t = threadIdx.x;
    const float* row = P + k * DIM;
    float a = row[t], b = row[t + 256];
    float ss = a * a + b * b;
    #pragma unroll
    for (int off = 32; off; off >>= 1) ss += __shfl_down(ss, off);
    int lane = t & 63, wid = t >> 6;
    if (lane == 0) red[wid] = ss;
    __syncthreads();
    if (t == 0) {
        float tot = red[0] + red[1] + red[2] + red[3];
        s_scale = 1.0f / fmaxf(sqrtf(tot), 1e-8f);
    }
    __syncthreads();
    float sc = s_scale;
    Ph[k * DIM + t]       = (f16)(a * sc);
    Ph[k * DIM + t + 256] = (f16)(b * sc);
}

// ---------------------------------------------------------------- assignment
__global__ __launch_bounds__(256) void assign_k(const float* __restrict__ F,
                                                const f16* __restrict__ Ph,
                                                unsigned char* __restrict__ asg,
                                                int* __restrict__ counts) {
    __shared__ f16   Al[CHUNK * APITCH];    // 33280 B
    __shared__ float sims[CHUNK * SPITCH];  //  8320 B
    __shared__ int   hist[KPROTO];

    int t    = threadIdx.x;
    int lane = t & 63;
    int wid  = t >> 6;       // wave id = proto tile
    int cq   = lane >> 4;    // quad
    int cl   = lane & 15;

    if (t < KPROTO) hist[t] = 0;

    // B fragments resident in registers: B[n = wid*16+cl][k = cq*8 + ks*32 + j]
    f16x8 bfrag[16];
    {
        const f16* pb = Ph + (wid * 16 + cl) * DIM + cq * 8;
        #pragma unroll
        for (int ks = 0; ks < 16; ++ks)
            bfrag[ks] = *(const f16x8*)(pb + ks * 32);
    }
    __syncthreads();

    for (int ch = blockIdx.x; ch < NCHUNKS; ch += gridDim.x) {
        // ---- stage 32 rows: 8 threads/row, each thread 16 contiguous float4
        {
            int r  = t >> 3;   // 0..31
            int c8 = t & 7;
            const float* src = F + (size_t)(ch * CHUNK + r) * DIM;
            f16* dst = Al + r * APITCH;
            #pragma unroll
            for (int j = 0; j < 16; ++j) {
                int cf4 = c8 + j * 8;              // float4 index 0..127
                f32x4 v = *(const f32x4*)(src + cf4 * 4);
                f16x4 h;
                h.x = (f16)v.x; h.y = (f16)v.y; h.z = (f16)v.z; h.w = (f16)v.w;
                *(f16x4*)(dst + cf4 * 4) = h;
            }
        }
        __syncthreads();

        // ---- MFMA: 2 rowtiles of 16 rows
        #pragma unroll
        for (int rt = 0; rt < 2; ++rt) {
            f32x4 acc = {0.f, 0.f, 0.f, 0.f};
            const f16* arow = Al + (rt * 16 + cl) * APITCH + cq * 8;
            #pragma unroll
            for (int ks = 0; ks < 16; ++ks) {
                f16x8 a = *(const f16x8*)(arow + ks * 32);
                acc = __builtin_amdgcn_mfma_f32_16x16x32_f16(a, bfrag[ks], acc, 0, 0, 0);
            }
            // D layout: col = lane&15, row = quad*4 + reg
            #pragma unroll
            for (int r = 0; r < 4; ++r) {
                int row = rt * 16 + cq * 4 + r;
                sims[row * SPITCH + wid * 16 + cl] = acc[r];
            }
        }
        __syncthreads();

        // ---- argmax per row: 2 threads/row, halves combined via shfl_xor.
        if (t < 64) {
            int row  = t >> 1;
            int half = t & 1;
            const float* srow = sims + row * SPITCH + half * 32;
            float best = srow[0];
            int bi = 0;
            #pragma unroll 8
            for (int j = 1; j < 32; ++j) {
                float v = srow[j];
                if (v > best) { best = v; bi = j; }
            }
            bi += half * 32;
            float obest = __shfl_xor(best, 1);
            int   obi   = __shfl_xor(bi, 1);
            if (obest > best || (obest == best && obi < bi)) { best = obest; bi = obi; }
            if (half == 0) {
                asg[ch * CHUNK + row] = (unsigned char)bi;
                atomicAdd(&hist[bi], 1);
            }
        }
    }
    __syncthreads();
    if (t < KPROTO) atomicAdd(&counts[t], hist[t]);
}

// ---------------------------------------------------------------- segment sum
// Column-sliced: block handles 128 of 512 dims -> 32 KB LDS acc.
// Lane owns dims {lane, lane+64} of its slice: LDS-atomic bank = lane%32,
// deterministic 2-way alias (free) independent of the proto index.
// STORE=1: flush partials with plain coalesced stores (no global atomics).
// STORE=0: legacy atomic flush (ws too small for partials).
template<int STORE>
__global__ __launch_bounds__(256) void segsum_k(const float* __restrict__ F,
                                                const unsigned char* __restrict__ asg,
                                                float* __restrict__ dst,
                                                int groups) {
    __shared__ float acc[KPROTO * 128];   // 32 KB
    int t     = threadIdx.x;
    int slice = blockIdx.x & 3;
    int group = blockIdx.x >> 2;
    #pragma unroll
    for (int m = 0; m < 32; ++m) acc[t + m * 256] = 0.0f;
    __syncthreads();

    int lane = t & 63, wid = t >> 6;
    int W = groups * 4;                   // total waves in this slice family
    int w = group * 4 + wid;
    const float* Fc = F + slice * 128 + lane;

    for (int r0 = w; r0 < N_FEAT; r0 += 8 * W) {
        float x[8], y[8];
        int a[8];
        #pragma unroll
        for (int u = 0; u < 8; ++u) {
            int r = r0 + u * W;
            if (r < N_FEAT) {
                a[u] = asg[r];
                const float* p = Fc + (size_t)r * DIM;
                x[u] = p[0];              // dim slice*128 + lane       (256B coalesced)
                y[u] = p[64];             // dim slice*128 + lane + 64  (256B coalesced)
            } else a[u] = -1;
        }
        #pragma unroll
        for (int u = 0; u < 8; ++u) {
            if (a[u] >= 0) {
                float* p = acc + a[u] * 128 + lane;
                atomicAdd(p,      x[u]);  // ds_add, bank = lane%32 : 2-way (free)
                atomicAdd(p + 64, y[u]);
            }
        }
    }
    __syncthreads();

    if (STORE) {
        // Plain coalesced float4 stores of this block's 32 KB partial.
        const f32x4* a4 = (const f32x4*)acc;
        f32x4* p4 = (f32x4*)dst + (size_t)blockIdx.x * 2048;
        #pragma unroll
        for (int m = 0; m < 8; ++m)
            p4[t + m * 256] = a4[t + m * 256];
    } else {
        // Legacy: global atomic flush (staggered).
        unsigned start = (blockIdx.x * 1237u) & 8191u;
        #pragma unroll
        for (int m = 0; m < 32; ++m) {
            unsigned idx = (start + t + m * 256u) & 8191u;   // 0..8191
            int k = idx >> 7, i = idx & 127;
            atomicAdd(&dst[k * DIM + slice * 128 + i], acc[idx]);
        }
    }
}

// ---------------------------------------------------------------- EMA epilogue
// RED=1: src = part[nb][8192]; reduce groups partials per slice, then EMA.
// RED=0: src = sums[64][512] directly.
template<int RED>
__global__ __launch_bounds__(256) void ema_k(const float* __restrict__ P,
                                             const float* __restrict__ src,
                                             const int* __restrict__ counts,
                                             float* __restrict__ out,
                                             int groups) {
    int idx = blockIdx.x * 256 + threadIdx.x;   // 0..32767
    int k = idx >> 9;
    float p = P[idx];
    int c = counts[k];
    float s;
    if (RED) {
        int d = idx & 511;
        int sl = d >> 7, i = d & 127;
        // partials for slice sl live in blocks b = sl + 4*g
        const float* q = src + (size_t)sl * 8192 + k * 128 + i;
        float acc0 = 0.f, acc1 = 0.f, acc2 = 0.f, acc3 = 0.f;
        for (int g = 0; g < groups; g += 4) {
            acc0 += q[(size_t)(4 * g +  0) * 8192];
            acc1 += q[(size_t)(4 * g +  4) * 8192];
            acc2 += q[(size_t)(4 * g +  8) * 8192];
            acc3 += q[(size_t)(4 * g + 12) * 8192];
        }
        s = (acc0 + acc1) + (acc2 + acc3);
    } else {
        s = src[idx];
    }
    float o = p;
    if (c > 0) o = 0.9f * p + 0.1f * (s / (float)c);
    out[idx] = o;
}

// ---------------------------------------------------------------- launch
extern "C" void kernel_launch(void* const* d_in, const int* in_sizes, int n_in,
                              void* d_out, int out_size, void* d_ws, size_t ws_size,
                              hipStream_t stream) {
    const float* F = (const float*)d_in[0];   // [200000][512]
    const float* P = (const float*)d_in[1];   // [64][512]
    char* ws = (char*)d_ws;
    f16*   Ph     = (f16*)(ws + WS_PH);
    int*   counts = (int*)(ws + WS_COUNTS);
    unsigned char* asg = (unsigned char*)(ws + WS_ASG);
    float* bulk   = (float*)(ws + WS_BULK);
    float* out = (float*)d_out;

    // Pick largest partial grid the workspace can hold (store path),
    // else fall back to the atomic flush.
    int nb = 0;
    if      (ws_size >= (size_t)WS_BULK + 1024ull * 32768) nb = 1024;
    else if (ws_size >= (size_t)WS_BULK +  512ull * 32768) nb = 512;
    else if (ws_size >= (size_t)WS_BULK +  256ull * 32768) nb = 256;

    hipMemsetAsync(counts, 0, KPROTO * sizeof(int), stream);

    proto_prep<<<KPROTO, 256, 0, stream>>>(P, Ph);
    assign_k<<<768, 256, 0, stream>>>(F, Ph, asg, counts);

    if (nb) {
        int groups = nb / 4;
        segsum_k<1><<<nb, 256, 0, stream>>>(F, asg, bulk, groups);
        ema_k<1><<<(KPROTO * DIM) / 256, 256, 0, stream>>>(P, bulk, counts, out, groups);
    } else {
        hipMemsetAsync(bulk, 0, KPROTO * DIM * sizeof(float), stream);
        int groups = 256;
        segsum_k<0><<<groups * 4, 256, 0, stream>>>(F, asg, bulk, groups);
        ema_k<0><<<(KPROTO * DIM) / 256, 256, 0, stream>>>(P, bulk, counts, out, groups);
    }
}

// Round 4
// 570.718 us; speedup vs baseline: 1.8757x; 1.8757x over previous
//
#include <hip/hip_runtime.h>

// Problem constants (fixed by the reference).
#define N_FEAT  200000
#define DIM     512
#define KPROTO  64
#define CH      16                 // rows per fused iteration
#define NITER   (N_FEAT / CH)      // 12500, exact
#define APITCH  520                // f16 elems per LDS row (1040 B)
#define SPITCH  65                 // sims pitch (dwords)

typedef _Float16 f16;
typedef _Float16 f16x8 __attribute__((ext_vector_type(8)));
typedef _Float16 f16x4 __attribute__((ext_vector_type(4)));
typedef float    f32x4 __attribute__((ext_vector_type(4)));

// ws layout (bytes):
//   [0,     65536) : p_h    f16 [64][512]    normalized prototypes
//   [65536, 65792) : counts int [64]
//   [66560, ...)   : part   f32 [nblk][64*512] per-block partial sums
#define WS_PH     0
#define WS_COUNTS 65536
#define WS_PART   66560

// ---------------------------------------------------------------- proto prep
__global__ __launch_bounds__(256) void proto_prep(const float* __restrict__ P,
                                                  f16* __restrict__ Ph) {
    __shared__ float red[4];
    __shared__ float s_scale;
    int k = blockIdx.x;
    int t = threadIdx.x;
    const float* row = P + k * DIM;
    float a = row[t], b = row[t + 256];
    float ss = a * a + b * b;
    #pragma unroll
    for (int off = 32; off; off >>= 1) ss += __shfl_down(ss, off);
    int lane = t & 63, wid = t >> 6;
    if (lane == 0) red[wid] = ss;
    __syncthreads();
    if (t == 0) {
        float tot = red[0] + red[1] + red[2] + red[3];
        s_scale = 1.0f / fmaxf(sqrtf(tot), 1e-8f);
    }
    __syncthreads();
    float sc = s_scale;
    Ph[k * DIM + t]       = (f16)(a * sc);
    Ph[k * DIM + t + 256] = (f16)(b * sc);
}

// ---------------------------------------------------------------- fused pass
// One kernel reads F exactly once. Per 16-row iteration:
//   prefetched regs -> f16 LDS stage -> MFMA sims -> argmax -> LDS accumulate.
// acc[64][512] f32 lives in LDS (128 KB); accumulation is atomic-free:
// thread t exclusively owns dims {t, t+256} of every prototype row.
// LDS total = 131072 + 16640 + 4160 + 64 + 256 = 152.2 KB -> 1 block/CU.
__global__ __launch_bounds__(256) void fused_k(const float* __restrict__ F,
                                               const f16* __restrict__ Ph,
                                               int* __restrict__ counts,
                                               float* __restrict__ part) {
    __shared__ float acc[KPROTO * DIM];     // 131072 B
    __shared__ f16   Al[CH * APITCH];       //  16640 B
    __shared__ float sims[CH * SPITCH];     //   4160 B
    __shared__ int   sasg[CH];
    __shared__ int   hist[KPROTO];

    int t    = threadIdx.x;
    int lane = t & 63;
    int wid  = t >> 6;       // wave id = 16-proto tile
    int cq   = lane >> 4;    // quad
    int cl   = lane & 15;

    #pragma unroll
    for (int m = 0; m < 128; ++m) acc[t + m * 256] = 0.0f;
    if (t < KPROTO) hist[t] = 0;

    // B fragments resident in registers: B[n = wid*16+cl][k = cq*8 + ks*32 + j]
    f16x8 bfrag[16];
    {
        const f16* pb = Ph + (wid * 16 + cl) * DIM + cq * 8;
        #pragma unroll
        for (int ks = 0; ks < 16; ++ks)
            bfrag[ks] = *(const f16x8*)(pb + ks * 32);
    }

    int r   = t >> 4;        // staged row 0..15 (16 threads/row)
    int c16 = t & 15;        // float4 column group

    f32x4 v[8];              // prefetch registers: 8 float4 = this thread's slice
    int it = blockIdx.x;
    const int GS = gridDim.x;
    if (it < NITER) {
        const float* src = F + ((size_t)it * CH + r) * DIM + c16 * 4;
        #pragma unroll
        for (int j = 0; j < 8; ++j) v[j] = *(const f32x4*)(src + j * 64);
    }
    __syncthreads();         // acc/hist zero visible

    for (; it < NITER; it += GS) {
        // ---- stage prefetched rows as f16
        {
            f16* dst = Al + r * APITCH + c16 * 4;
            #pragma unroll
            for (int j = 0; j < 8; ++j) {
                f16x4 h;
                h.x = (f16)v[j].x; h.y = (f16)v[j].y;
                h.z = (f16)v[j].z; h.w = (f16)v[j].w;
                *(f16x4*)(dst + j * 64) = h;
            }
        }
        // ---- issue next iteration's loads (land during compute phases)
        {
            int nx = it + GS;
            if (nx < NITER) {
                const float* src = F + ((size_t)nx * CH + r) * DIM + c16 * 4;
                #pragma unroll
                for (int j = 0; j < 8; ++j) v[j] = *(const f32x4*)(src + j * 64);
            }
        }
        __syncthreads();     // Al ready

        // ---- MFMA: 16 rows x (wave's 16 protos), K=512
        {
            f32x4 a2 = {0.f, 0.f, 0.f, 0.f};
            const f16* arow = Al + cl * APITCH + cq * 8;
            #pragma unroll
            for (int ks = 0; ks < 16; ++ks) {
                f16x8 a = *(const f16x8*)(arow + ks * 32);
                a2 = __builtin_amdgcn_mfma_f32_16x16x32_f16(a, bfrag[ks], a2, 0, 0, 0);
            }
            // D layout: col = lane&15 (proto), row = quad*4 + reg
            #pragma unroll
            for (int q = 0; q < 4; ++q)
                sims[(cq * 4 + q) * SPITCH + wid * 16 + cl] = a2[q];
        }
        __syncthreads();     // sims ready

        // ---- argmax per row: 2 threads/row (first-max tie-break = jnp.argmax)
        if (t < 32) {
            int row  = t >> 1;
            int half = t & 1;
            const float* srow = sims + row * SPITCH + half * 32;
            float best = srow[0];
            int bi = 0;
            #pragma unroll 8
            for (int j = 1; j < 32; ++j) {
                float x = srow[j];
                if (x > best) { best = x; bi = j; }
            }
            bi += half * 32;
            float ob = __shfl_xor(best, 1);
            int   oi = __shfl_xor(bi, 1);
            if (ob > best || (ob == best && oi < bi)) { best = ob; bi = oi; }
            if (half == 0) { sasg[row] = bi; atomicAdd(&hist[bi], 1); }
        }
        __syncthreads();     // sasg ready

        // ---- accumulate staged rows into acc (atomic-free, owner-column)
        #pragma unroll
        for (int rr = 0; rr < CH; ++rr) {
            int a = sasg[rr];
            float v0 = (float)Al[rr * APITCH + t];        // dim t
            float v1 = (float)Al[rr * APITCH + t + 256];  // dim t+256
            float* p = acc + a * DIM + t;
            p[0]   += v0;    // only thread t ever touches column t
            p[256] += v1;
        }
        __syncthreads();     // Al free for next stage
    }

    // ---- flush per-block partial (plain coalesced stores) + counts
    {
        f32x4* d4 = (f32x4*)(part + (size_t)blockIdx.x * (KPROTO * DIM));
        const f32x4* a4 = (const f32x4*)acc;
        #pragma unroll
        for (int m = 0; m < 32; ++m) d4[t + m * 256] = a4[t + m * 256];
    }
    if (t < KPROTO) atomicAdd(&counts[t], hist[t]);
}

// ---------------------------------------------------------------- EMA epilogue
// Reduce npart per-block partials per element, then EMA.
__global__ __launch_bounds__(256) void ema_k(const float* __restrict__ P,
                                             const float* __restrict__ part,
                                             const int* __restrict__ counts,
                                             float* __restrict__ out,
                                             int npart) {
    int idx = blockIdx.x * 256 + threadIdx.x;   // 0..32767
    int k = idx >> 9;
    float p = P[idx];
    int c = counts[k];
    const float* q = part + idx;
    float a0 = 0.f, a1 = 0.f, a2 = 0.f, a3 = 0.f;
    for (int g = 0; g < npart; g += 4) {        // npart multiple of 4
        a0 += q[(size_t)(g + 0) * (KPROTO * DIM)];
        a1 += q[(size_t)(g + 1) * (KPROTO * DIM)];
        a2 += q[(size_t)(g + 2) * (KPROTO * DIM)];
        a3 += q[(size_t)(g + 3) * (KPROTO * DIM)];
    }
    float s = (a0 + a1) + (a2 + a3);
    float o = p;
    if (c > 0) o = 0.9f * p + 0.1f * (s / (float)c);
    out[idx] = o;
}

// ---------------------------------------------------------------- launch
extern "C" void kernel_launch(void* const* d_in, const int* in_sizes, int n_in,
                              void* d_out, int out_size, void* d_ws, size_t ws_size,
                              hipStream_t stream) {
    const float* F = (const float*)d_in[0];   // [200000][512]
    const float* P = (const float*)d_in[1];   // [64][512]
    char* ws = (char*)d_ws;
    f16*   Ph     = (f16*)(ws + WS_PH);
    int*   counts = (int*)(ws + WS_COUNTS);
    float* part   = (float*)(ws + WS_PART);
    float* out    = (float*)d_out;

    // Partial-buffer grid sized to workspace (256 known to fit from round 3).
    int nblk = 256;
    while (nblk > 32 &&
           ws_size < (size_t)WS_PART + (size_t)nblk * KPROTO * DIM * sizeof(float))
        nblk >>= 1;

    hipMemsetAsync(counts, 0, KPROTO * sizeof(int), stream);

    proto_prep<<<KPROTO, 256, 0, stream>>>(P, Ph);
    fused_k<<<nblk, 256, 0, stream>>>(F, Ph, counts, part);
    ema_k<<<(KPROTO * DIM) / 256, 256, 0, stream>>>(P, part, counts, out, nblk);
}